// Round 6
// baseline (73.741 us; speedup 1.0000x reference)
//
#include <hip/hip_runtime.h>

// ZNCC 5x5, zero-padded, count_include_pad means.
// x,y: (4,3,512,512) f32 -> out: (4,1,512,512) f32
// Round 6: channel parallelism in the GRID. One 256-thread block per
// (batch, channel, 64x16 tile) -> 3072 blocks, 4 waves/block, 10.9KB LDS
// -> 8 blocks/CU = 32 waves/CU (100% occupancy ceiling). Cross-channel
// reduction via memset + native f32 atomicAdd (3 adds/output, v/3 pre-scaled).

constexpr int W  = 512, H = 512, C = 3, NB = 4;
constexpr int TW = 64, TH = 16, HALO = 2;
constexpr int LW = TW + 2 * HALO;   // 68 (float4 alignment kept: 4*tx base, 272B rows)
constexpr int LH = TH + 2 * HALO;   // 20
constexpr int LSZ = LW * LH;        // 1360

__global__ __launch_bounds__(256, 8)
void zncc_kernel(const float* __restrict__ x,
                 const float* __restrict__ y,
                 float* __restrict__ out) {
    __shared__ float sx[LSZ];
    __shared__ float sy[LSZ];

    const int tid = threadIdx.x;
    const int tx  = tid & 15;    // 16 thread-cols x 4 px = 64 cols
    const int ty  = tid >> 4;    // 16 rows
    const int w0  = blockIdx.x * TW;
    const int h0  = blockIdx.y * TH;
    const int bc  = blockIdx.z;          // b*C + c
    const float EPS = 1e-4f;

    // ---- stage this channel's zero-padded 20x68 x,y tiles ----
    {
        const float* __restrict__ xb = x + (size_t)bc * (H * W);
        const float* __restrict__ yb = y + (size_t)bc * (H * W);
        for (int i = tid; i < LSZ; i += 256) {
            const int l  = i / LW;
            const int m  = i - l * LW;
            const int gr = h0 + l - HALO;
            const int gc = w0 + m - HALO;
            const bool ok = ((unsigned)gr < (unsigned)H) && ((unsigned)gc < (unsigned)W);
            const int gi = gr * W + gc;
            sx[i] = ok ? xb[gi] : 0.f;
            sy[i] = ok ? yb[gi] : 0.f;
        }
    }
    __syncthreads();

    // ---- pass A: 5x5 sums for my 4 pixels (sliding row sums) ----
    float sxs[4] = {0.f, 0.f, 0.f, 0.f};
    float sys[4] = {0.f, 0.f, 0.f, 0.f};
    #pragma unroll
    for (int r = 0; r < 5; ++r) {
        const int base = (ty + r) * LW + 4 * tx;
        const float4 a0 = *reinterpret_cast<const float4*>(&sx[base]);
        const float4 a1 = *reinterpret_cast<const float4*>(&sx[base + 4]);
        const float4 b0 = *reinterpret_cast<const float4*>(&sy[base]);
        const float4 b1 = *reinterpret_cast<const float4*>(&sy[base + 4]);
        const float rx[8] = {a0.x, a0.y, a0.z, a0.w, a1.x, a1.y, a1.z, a1.w};
        const float ry[8] = {b0.x, b0.y, b0.z, b0.w, b1.x, b1.y, b1.z, b1.w};
        float s = rx[0] + rx[1] + rx[2] + rx[3] + rx[4];
        sxs[0] += s; s += rx[5] - rx[0];
        sxs[1] += s; s += rx[6] - rx[1];
        sxs[2] += s; s += rx[7] - rx[2];
        sxs[3] += s;
        float t = ry[0] + ry[1] + ry[2] + ry[3] + ry[4];
        sys[0] += t; t += ry[5] - ry[0];
        sys[1] += t; t += ry[6] - ry[1];
        sys[2] += t; t += ry[7] - ry[2];
        sys[3] += t;
    }
    float mx[4], my[4];
    #pragma unroll
    for (int p = 0; p < 4; ++p) {
        mx[p] = sxs[p] * (1.f / 25.f);
        my[p] = sys[p] * (1.f / 25.f);
    }

    // ---- pass B: ncc accumulation ----
    float acc[4] = {0.f, 0.f, 0.f, 0.f};
    #pragma unroll
    for (int r = 0; r < 5; ++r) {
        const int base = (ty + r) * LW + 4 * tx;
        const float4 a0 = *reinterpret_cast<const float4*>(&sx[base]);
        const float4 a1 = *reinterpret_cast<const float4*>(&sx[base + 4]);
        const float4 b0 = *reinterpret_cast<const float4*>(&sy[base]);
        const float4 b1 = *reinterpret_cast<const float4*>(&sy[base + 4]);
        const float rx[8] = {a0.x, a0.y, a0.z, a0.w, a1.x, a1.y, a1.z, a1.w};
        const float ry[8] = {b0.x, b0.y, b0.z, b0.w, b1.x, b1.y, b1.z, b1.w};
        #pragma unroll
        for (int p = 0; p < 4; ++p) {
            #pragma unroll
            for (int j = 0; j < 5; ++j) {
                const float dx  = rx[p + j] - mx[p];
                const float dy  = ry[p + j] - my[p];
                const float num = fabsf(dx * dy) + EPS;
                const float den = (dx * dx + EPS) * (dy * dy + EPS);
                acc[p] += num * __builtin_amdgcn_rsqf(den);
            }
        }
    }

    // ---- clip, pre-scale by 1/3, atomic-accumulate into output ----
    const int b    = bc / C;               // batch (block-uniform)
    const int orow = h0 + ty;
    float* op = &out[((size_t)b * H + orow) * W + w0 + 4 * tx];
    #pragma unroll
    for (int p = 0; p < 4; ++p) {
        float v = acc[p] * (1.f / 25.f);
        v = fminf(fmaxf(v, 0.f), 1.f) * (1.f / 3.f);
        unsafeAtomicAdd(op + p, v);        // native global_atomic_add_f32
    }
}

extern "C" void kernel_launch(void* const* d_in, const int* in_sizes, int n_in,
                              void* d_out, int out_size, void* d_ws, size_t ws_size,
                              hipStream_t stream) {
    const float* x = (const float*)d_in[0];
    const float* y = (const float*)d_in[1];
    float* out = (float*)d_out;
    hipMemsetAsync(out, 0, (size_t)out_size * sizeof(float), stream);
    dim3 grid(W / TW, H / TH, NB * C);   // 8, 32, 12 = 3072 blocks (8/CU resident)
    zncc_kernel<<<grid, dim3(256), 0, stream>>>(x, y, out);
}

// Round 7
// 61.019 us; speedup vs baseline: 1.2085x; 1.2085x over previous
//
#include <hip/hip_runtime.h>

// ZNCC 5x5, zero-padded, count_include_pad means.
// x,y: (4,3,512,512) f32 -> out: (4,1,512,512) f32
// Round 7: round-6 grid channel-parallelism (3072 blocks, 1 stage + 1 barrier
// + 1 channel per block, 8 blocks/CU) but reduction via COALESCED per-channel
// partials in d_ws + a tiny plane-sum kernel. No atomics (round 6's 190MB
// write amplification came from uncoalesced f32 atomics ping-ponging lines
// across XCD L2s). Fallback to the round-1 single-kernel path if ws too small.

constexpr int W  = 512, H = 512, C = 3, NB = 4;
constexpr int TW = 64, TH = 16, HALO = 2;
constexpr int LW = TW + 2 * HALO;   // 68 (float4 alignment kept: 4*tx base, 272B rows)
constexpr int LH = TH + 2 * HALO;   // 20
constexpr int LSZ = LW * LH;        // 1360
constexpr int PLANE = H * W;        // 262144 floats per (b,c) plane

// ---------------- shared compute body (one channel tile) ----------------
__device__ __forceinline__ float4 zncc_tile(const float* __restrict__ sx,
                                            const float* __restrict__ sy,
                                            int tx, int ty) {
    const float EPS = 1e-4f;

    // pass A: 5x5 sums for my 4 pixels (sliding row sums)
    float sxs[4] = {0.f, 0.f, 0.f, 0.f};
    float sys[4] = {0.f, 0.f, 0.f, 0.f};
    #pragma unroll
    for (int r = 0; r < 5; ++r) {
        const int base = (ty + r) * LW + 4 * tx;
        const float4 a0 = *reinterpret_cast<const float4*>(&sx[base]);
        const float4 a1 = *reinterpret_cast<const float4*>(&sx[base + 4]);
        const float4 b0 = *reinterpret_cast<const float4*>(&sy[base]);
        const float4 b1 = *reinterpret_cast<const float4*>(&sy[base + 4]);
        const float rx[8] = {a0.x, a0.y, a0.z, a0.w, a1.x, a1.y, a1.z, a1.w};
        const float ry[8] = {b0.x, b0.y, b0.z, b0.w, b1.x, b1.y, b1.z, b1.w};
        float s = rx[0] + rx[1] + rx[2] + rx[3] + rx[4];
        sxs[0] += s; s += rx[5] - rx[0];
        sxs[1] += s; s += rx[6] - rx[1];
        sxs[2] += s; s += rx[7] - rx[2];
        sxs[3] += s;
        float t = ry[0] + ry[1] + ry[2] + ry[3] + ry[4];
        sys[0] += t; t += ry[5] - ry[0];
        sys[1] += t; t += ry[6] - ry[1];
        sys[2] += t; t += ry[7] - ry[2];
        sys[3] += t;
    }
    float mx[4], my[4];
    #pragma unroll
    for (int p = 0; p < 4; ++p) {
        mx[p] = sxs[p] * (1.f / 25.f);
        my[p] = sys[p] * (1.f / 25.f);
    }

    // pass B: ncc accumulation
    float acc[4] = {0.f, 0.f, 0.f, 0.f};
    #pragma unroll
    for (int r = 0; r < 5; ++r) {
        const int base = (ty + r) * LW + 4 * tx;
        const float4 a0 = *reinterpret_cast<const float4*>(&sx[base]);
        const float4 a1 = *reinterpret_cast<const float4*>(&sx[base + 4]);
        const float4 b0 = *reinterpret_cast<const float4*>(&sy[base]);
        const float4 b1 = *reinterpret_cast<const float4*>(&sy[base + 4]);
        const float rx[8] = {a0.x, a0.y, a0.z, a0.w, a1.x, a1.y, a1.z, a1.w};
        const float ry[8] = {b0.x, b0.y, b0.z, b0.w, b1.x, b1.y, b1.z, b1.w};
        #pragma unroll
        for (int p = 0; p < 4; ++p) {
            #pragma unroll
            for (int j = 0; j < 5; ++j) {
                const float dx  = rx[p + j] - mx[p];
                const float dy  = ry[p + j] - my[p];
                const float num = fabsf(dx * dy) + EPS;
                const float den = (dx * dx + EPS) * (dy * dy + EPS);
                acc[p] += num * __builtin_amdgcn_rsqf(den);
            }
        }
    }
    float4 v;
    v.x = fminf(fmaxf(acc[0] * (1.f / 25.f), 0.f), 1.f);
    v.y = fminf(fmaxf(acc[1] * (1.f / 25.f), 0.f), 1.f);
    v.z = fminf(fmaxf(acc[2] * (1.f / 25.f), 0.f), 1.f);
    v.w = fminf(fmaxf(acc[3] * (1.f / 25.f), 0.f), 1.f);
    return v;
}

__device__ __forceinline__ void stage_tile(const float* __restrict__ xb,
                                           const float* __restrict__ yb,
                                           float* __restrict__ sx,
                                           float* __restrict__ sy,
                                           int h0, int w0, int tid) {
    for (int i = tid; i < LSZ; i += 256) {
        const int l  = i / LW;
        const int m  = i - l * LW;
        const int gr = h0 + l - HALO;
        const int gc = w0 + m - HALO;
        const bool ok = ((unsigned)gr < (unsigned)H) && ((unsigned)gc < (unsigned)W);
        const int gi = gr * W + gc;
        sx[i] = ok ? xb[gi] : 0.f;
        sy[i] = ok ? yb[gi] : 0.f;
    }
}

// ---------------- kernel 1: per-channel partial -> ws plane ----------------
__global__ __launch_bounds__(256, 8)
void zncc_partial(const float* __restrict__ x,
                  const float* __restrict__ y,
                  float* __restrict__ ws) {
    __shared__ float sx[LSZ];
    __shared__ float sy[LSZ];

    const int tid = threadIdx.x;
    const int tx  = tid & 15;
    const int ty  = tid >> 4;
    const int w0  = blockIdx.x * TW;
    const int h0  = blockIdx.y * TH;
    const int bc  = blockIdx.z;                  // b*C + c  (plane index)

    stage_tile(x + (size_t)bc * PLANE, y + (size_t)bc * PLANE, sx, sy, h0, w0, tid);
    __syncthreads();

    const float4 v = zncc_tile(sx, sy, tx, ty);
    *reinterpret_cast<float4*>(&ws[(size_t)bc * PLANE + (h0 + ty) * W + w0 + 4 * tx]) = v;
}

// ---------------- kernel 2: sum 3 planes -> out ----------------
__global__ __launch_bounds__(256)
void zncc_reduce(const float* __restrict__ ws, float* __restrict__ out) {
    const int g = blockIdx.x * 256 + threadIdx.x;     // 0 .. NB*PLANE/4-1
    const int b = g >> 16;                            // PLANE/4 = 65536 float4/batch
    const int r = g & 65535;
    const float4* w4 = reinterpret_cast<const float4*>(ws);
    const float4 p0 = w4[(size_t)(b * 3 + 0) * (PLANE / 4) + r];
    const float4 p1 = w4[(size_t)(b * 3 + 1) * (PLANE / 4) + r];
    const float4 p2 = w4[(size_t)(b * 3 + 2) * (PLANE / 4) + r];
    float4 o;
    o.x = (p0.x + p1.x + p2.x) * (1.f / 3.f);
    o.y = (p0.y + p1.y + p2.y) * (1.f / 3.f);
    o.z = (p0.z + p1.z + p2.z) * (1.f / 3.f);
    o.w = (p0.w + p1.w + p2.w) * (1.f / 3.f);
    reinterpret_cast<float4*>(out)[g] = o;
}

// ---------------- fallback: round-1 single kernel (champion, 47us) ----------
__global__ __launch_bounds__(256, 4)
void zncc_mono(const float* __restrict__ x,
               const float* __restrict__ y,
               float* __restrict__ out) {
    __shared__ float sx[LSZ];
    __shared__ float sy[LSZ];

    const int tid = threadIdx.x;
    const int tx  = tid & 15;
    const int ty  = tid >> 4;
    const int w0  = blockIdx.x * TW;
    const int h0  = blockIdx.y * TH;
    const int b   = blockIdx.z;

    float4 ca = make_float4(0.f, 0.f, 0.f, 0.f);
    for (int c = 0; c < C; ++c) {
        stage_tile(x + (size_t)(b * C + c) * PLANE, y + (size_t)(b * C + c) * PLANE,
                   sx, sy, h0, w0, tid);
        __syncthreads();
        const float4 v = zncc_tile(sx, sy, tx, ty);
        ca.x += v.x; ca.y += v.y; ca.z += v.z; ca.w += v.w;
        __syncthreads();
    }
    float4 o;
    o.x = ca.x * (1.f / 3.f);
    o.y = ca.y * (1.f / 3.f);
    o.z = ca.z * (1.f / 3.f);
    o.w = ca.w * (1.f / 3.f);
    *reinterpret_cast<float4*>(&out[((size_t)b * H + h0 + ty) * W + w0 + 4 * tx]) = o;
}

extern "C" void kernel_launch(void* const* d_in, const int* in_sizes, int n_in,
                              void* d_out, int out_size, void* d_ws, size_t ws_size,
                              hipStream_t stream) {
    const float* x = (const float*)d_in[0];
    const float* y = (const float*)d_in[1];
    float* out = (float*)d_out;

    const size_t need = (size_t)NB * C * PLANE * sizeof(float);   // 12.6 MB
    if (ws_size >= need) {
        float* ws = (float*)d_ws;
        dim3 g1(W / TW, H / TH, NB * C);          // 8, 32, 12 = 3072 blocks
        zncc_partial<<<g1, dim3(256), 0, stream>>>(x, y, ws);
        const int n4 = NB * PLANE / 4;            // 262144 float4 outputs
        zncc_reduce<<<dim3(n4 / 256), dim3(256), 0, stream>>>(ws, out);
    } else {
        dim3 g(W / TW, H / TH, NB);               // fallback: round-1 champion
        zncc_mono<<<g, dim3(256), 0, stream>>>(x, y, out);
    }
}

// Round 8
// 42.416 us; speedup vs baseline: 1.7385x; 1.4386x over previous
//
#include <hip/hip_runtime.h>

// ZNCC 5x5, zero-padded, count_include_pad means.
// x,y: (4,3,512,512) f32 -> out: (4,1,512,512) f32
// Round 8: vertical register sliding. Each thread owns a 2-col x 4-row output
// strip; a rolling 5x6 register window slides down so each LDS row is read
// ONCE (3x ds_read_b64 per array per output row vs 10 row-reads in round 1).
// Means from rolling column sums. Long unrolled VALU stream per row (~440 ops
// + 50 rsq) hides latency via ILP instead of occupancy. 512 blocks, 2/CU.

constexpr int W  = 512, H = 512, C = 3, NB = 4;
constexpr int TW = 64, TH = 32, HALO = 2;
constexpr int LW = TW + 2 * HALO;   // 68 (even -> float2 alignment kept)
constexpr int LH = TH + 2 * HALO;   // 36
constexpr int LSZ = LW * LH;        // 2448

__global__ __launch_bounds__(256, 2)
void zncc_kernel(const float* __restrict__ x,
                 const float* __restrict__ y,
                 float* __restrict__ out) {
    __shared__ float sx[LSZ];
    __shared__ float sy[LSZ];

    const int tid = threadIdx.x;
    const int tx  = tid & 31;        // 32 col-pairs -> 64 cols
    const int ry  = tid >> 5;        // 0..7 -> rows 4*ry .. 4*ry+3
    const int cx  = 2 * tx;          // output col offset within tile
    const int w0  = blockIdx.x * TW;
    const int h0  = blockIdx.y * TH;
    const int b   = blockIdx.z;
    const float EPS = 1e-4f;

    float ch0[4] = {0.f, 0.f, 0.f, 0.f};   // px0, rows 0..3 (channel-accumulated)
    float ch1[4] = {0.f, 0.f, 0.f, 0.f};   // px1

    for (int c = 0; c < C; ++c) {
        const float* __restrict__ xb = x + (size_t)(b * C + c) * (H * W);
        const float* __restrict__ yb = y + (size_t)(b * C + c) * (H * W);

        // ---- stage zero-padded 36x68 tiles ----
        for (int i = tid; i < LSZ; i += 256) {
            const int l  = i / LW;
            const int m  = i - l * LW;
            const int gr = h0 + l - HALO;
            const int gc = w0 + m - HALO;
            const bool ok = ((unsigned)gr < (unsigned)H) && ((unsigned)gc < (unsigned)W);
            const int gi = gr * W + gc;
            sx[i] = ok ? xb[gi] : 0.f;
            sy[i] = ok ? yb[gi] : 0.f;
        }
        __syncthreads();

        // ---- rolling 5x6 register window + column sums ----
        float bx[5][6], by[5][6];
        float csx[6], csy[6];

        // prologue: window rows 0..3 (LDS rows 4*ry+k), init column sums
        #pragma unroll
        for (int k = 0; k < 4; ++k) {
            const int base = (4 * ry + k) * LW + cx;
            const float2 u0 = *reinterpret_cast<const float2*>(&sx[base]);
            const float2 u1 = *reinterpret_cast<const float2*>(&sx[base + 2]);
            const float2 u2 = *reinterpret_cast<const float2*>(&sx[base + 4]);
            const float2 v0 = *reinterpret_cast<const float2*>(&sy[base]);
            const float2 v1 = *reinterpret_cast<const float2*>(&sy[base + 2]);
            const float2 v2 = *reinterpret_cast<const float2*>(&sy[base + 4]);
            bx[k][0] = u0.x; bx[k][1] = u0.y; bx[k][2] = u1.x;
            bx[k][3] = u1.y; bx[k][4] = u2.x; bx[k][5] = u2.y;
            by[k][0] = v0.x; by[k][1] = v0.y; by[k][2] = v1.x;
            by[k][3] = v1.y; by[k][4] = v2.x; by[k][5] = v2.y;
            #pragma unroll
            for (int j = 0; j < 6; ++j) {
                if (k == 0) { csx[j] = bx[0][j];  csy[j] = by[0][j]; }
                else        { csx[j] += bx[k][j]; csy[j] += by[k][j]; }
            }
        }

        // slide over 4 output rows
        #pragma unroll
        for (int o = 0; o < 4; ++o) {
            // load incoming window row o+4 into slot (o+4)%5
            const int sN   = (o + 4) % 5;
            const int base = (4 * ry + o + 4) * LW + cx;
            {
                const float2 u0 = *reinterpret_cast<const float2*>(&sx[base]);
                const float2 u1 = *reinterpret_cast<const float2*>(&sx[base + 2]);
                const float2 u2 = *reinterpret_cast<const float2*>(&sx[base + 4]);
                const float2 v0 = *reinterpret_cast<const float2*>(&sy[base]);
                const float2 v1 = *reinterpret_cast<const float2*>(&sy[base + 2]);
                const float2 v2 = *reinterpret_cast<const float2*>(&sy[base + 4]);
                bx[sN][0] = u0.x; bx[sN][1] = u0.y; bx[sN][2] = u1.x;
                bx[sN][3] = u1.y; bx[sN][4] = u2.x; bx[sN][5] = u2.y;
                by[sN][0] = v0.x; by[sN][1] = v0.y; by[sN][2] = v1.x;
                by[sN][3] = v1.y; by[sN][4] = v2.x; by[sN][5] = v2.y;
            }
            #pragma unroll
            for (int j = 0; j < 6; ++j) { csx[j] += bx[sN][j]; csy[j] += by[sN][j]; }

            // means for the 2 pixels (windows cols 0..4 and 1..5)
            const float m4x = csx[1] + csx[2] + csx[3] + csx[4];
            const float m4y = csy[1] + csy[2] + csy[3] + csy[4];
            const float mx0 = (m4x + csx[0]) * (1.f / 25.f);
            const float mx1 = (m4x + csx[5]) * (1.f / 25.f);
            const float my0 = (m4y + csy[0]) * (1.f / 25.f);
            const float my1 = (m4y + csy[5]) * (1.f / 25.f);

            // 25 ncc terms per pixel
            float a0 = 0.f, a1 = 0.f;
            #pragma unroll
            for (int k = 0; k < 5; ++k) {
                const int s = (o + k) % 5;
                #pragma unroll
                for (int j = 0; j < 5; ++j) {
                    {
                        const float dx  = bx[s][j] - mx0;
                        const float dy  = by[s][j] - my0;
                        const float num = fabsf(dx * dy) + EPS;
                        const float den = (dx * dx + EPS) * (dy * dy + EPS);
                        a0 += num * __builtin_amdgcn_rsqf(den);
                    }
                    {
                        const float dx  = bx[s][j + 1] - mx1;
                        const float dy  = by[s][j + 1] - my1;
                        const float num = fabsf(dx * dy) + EPS;
                        const float den = (dx * dx + EPS) * (dy * dy + EPS);
                        a1 += num * __builtin_amdgcn_rsqf(den);
                    }
                }
            }
            ch0[o] += fminf(fmaxf(a0 * (1.f / 25.f), 0.f), 1.f);
            ch1[o] += fminf(fmaxf(a1 * (1.f / 25.f), 0.f), 1.f);

            // retire oldest window row (slot o%5) from column sums
            const int sO = o % 5;
            #pragma unroll
            for (int j = 0; j < 6; ++j) { csx[j] -= bx[sO][j]; csy[j] -= by[sO][j]; }
        }
        __syncthreads();   // everyone done reading before next channel's staging
    }

    // ---- write 2x4 output strip ----
    #pragma unroll
    for (int o = 0; o < 4; ++o) {
        float2 v;
        v.x = ch0[o] * (1.f / 3.f);
        v.y = ch1[o] * (1.f / 3.f);
        *reinterpret_cast<float2*>(
            &out[((size_t)b * H + h0 + 4 * ry + o) * W + w0 + cx]) = v;
    }
}

extern "C" void kernel_launch(void* const* d_in, const int* in_sizes, int n_in,
                              void* d_out, int out_size, void* d_ws, size_t ws_size,
                              hipStream_t stream) {
    const float* x = (const float*)d_in[0];
    const float* y = (const float*)d_in[1];
    float* out = (float*)d_out;
    dim3 grid(W / TW, H / TH, NB);   // 8, 16, 4 = 512 blocks (2 per CU)
    zncc_kernel<<<grid, dim3(256), 0, stream>>>(x, y, out);
}

// Round 9
// 34.249 us; speedup vs baseline: 2.1531x; 1.2385x over previous
//
#include <hip/hip_runtime.h>

// ZNCC 5x5, zero-padded, count_include_pad means.
// x,y: (4,3,512,512) f32 -> out: (4,1,512,512) f32
// Round 9: R8 vertical-register-sliding body + software-pipelined channel
// staging: double-buffered LDS (1 barrier/channel), register-prefetch of
// channel c+1 issued BEFORE compute of channel c (HBM latency hidden under
// ~5K cycles of compute), staging address math hoisted out of the channel
// loop (goff/fm precomputed once). Grid pins residency at 2 waves/SIMD, so
// the extra ~40 VGPRs are free.

constexpr int W  = 512, H = 512, C = 3, NB = 4;
constexpr int PLANE = H * W;
constexpr int TW = 64, TH = 32, HALO = 2;
constexpr int LW = TW + 2 * HALO;   // 68
constexpr int LH = TH + 2 * HALO;   // 36
constexpr int LSZ  = LW * LH;       // 2448
constexpr int LPAD = 2560;          // 10 chunks * 256 threads (pad absorbs tail)
constexpr int NPF  = 10;            // prefetch regs per array per thread

__device__ __forceinline__ void prefetch_plane(const float* __restrict__ pb,
                                               const int* goff, const float* fm,
                                               float* r) {
    #pragma unroll
    for (int k = 0; k < NPF; ++k) r[k] = pb[goff[k]] * fm[k];
}

__device__ __forceinline__ void write_tile(float* __restrict__ dst,
                                           const float* r, int tid) {
    #pragma unroll
    for (int k = 0; k < NPF; ++k) dst[tid + 256 * k] = r[k];
}

// R8 compute body: rolling 5x6 register window over a staged 36x68 tile.
__device__ __forceinline__ void compute_channel(const float* __restrict__ bxs,
                                                const float* __restrict__ bys,
                                                int ry, int cx,
                                                float* ch0, float* ch1) {
    const float EPS = 1e-4f;
    float bx[5][6], by[5][6];
    float csx[6], csy[6];

    #pragma unroll
    for (int k = 0; k < 4; ++k) {
        const int base = (4 * ry + k) * LW + cx;
        const float2 u0 = *reinterpret_cast<const float2*>(&bxs[base]);
        const float2 u1 = *reinterpret_cast<const float2*>(&bxs[base + 2]);
        const float2 u2 = *reinterpret_cast<const float2*>(&bxs[base + 4]);
        const float2 v0 = *reinterpret_cast<const float2*>(&bys[base]);
        const float2 v1 = *reinterpret_cast<const float2*>(&bys[base + 2]);
        const float2 v2 = *reinterpret_cast<const float2*>(&bys[base + 4]);
        bx[k][0] = u0.x; bx[k][1] = u0.y; bx[k][2] = u1.x;
        bx[k][3] = u1.y; bx[k][4] = u2.x; bx[k][5] = u2.y;
        by[k][0] = v0.x; by[k][1] = v0.y; by[k][2] = v1.x;
        by[k][3] = v1.y; by[k][4] = v2.x; by[k][5] = v2.y;
        #pragma unroll
        for (int j = 0; j < 6; ++j) {
            if (k == 0) { csx[j] = bx[0][j];  csy[j] = by[0][j]; }
            else        { csx[j] += bx[k][j]; csy[j] += by[k][j]; }
        }
    }

    #pragma unroll
    for (int o = 0; o < 4; ++o) {
        const int sN   = (o + 4) % 5;
        const int base = (4 * ry + o + 4) * LW + cx;
        {
            const float2 u0 = *reinterpret_cast<const float2*>(&bxs[base]);
            const float2 u1 = *reinterpret_cast<const float2*>(&bxs[base + 2]);
            const float2 u2 = *reinterpret_cast<const float2*>(&bxs[base + 4]);
            const float2 v0 = *reinterpret_cast<const float2*>(&bys[base]);
            const float2 v1 = *reinterpret_cast<const float2*>(&bys[base + 2]);
            const float2 v2 = *reinterpret_cast<const float2*>(&bys[base + 4]);
            bx[sN][0] = u0.x; bx[sN][1] = u0.y; bx[sN][2] = u1.x;
            bx[sN][3] = u1.y; bx[sN][4] = u2.x; bx[sN][5] = u2.y;
            by[sN][0] = v0.x; by[sN][1] = v0.y; by[sN][2] = v1.x;
            by[sN][3] = v1.y; by[sN][4] = v2.x; by[sN][5] = v2.y;
        }
        #pragma unroll
        for (int j = 0; j < 6; ++j) { csx[j] += bx[sN][j]; csy[j] += by[sN][j]; }

        const float m4x = csx[1] + csx[2] + csx[3] + csx[4];
        const float m4y = csy[1] + csy[2] + csy[3] + csy[4];
        const float mx0 = (m4x + csx[0]) * (1.f / 25.f);
        const float mx1 = (m4x + csx[5]) * (1.f / 25.f);
        const float my0 = (m4y + csy[0]) * (1.f / 25.f);
        const float my1 = (m4y + csy[5]) * (1.f / 25.f);

        float a0 = 0.f, a1 = 0.f;
        #pragma unroll
        for (int k = 0; k < 5; ++k) {
            const int s = (o + k) % 5;
            #pragma unroll
            for (int j = 0; j < 5; ++j) {
                {
                    const float dx  = bx[s][j] - mx0;
                    const float dy  = by[s][j] - my0;
                    const float num = fabsf(dx * dy) + EPS;
                    const float den = (dx * dx + EPS) * (dy * dy + EPS);
                    a0 += num * __builtin_amdgcn_rsqf(den);
                }
                {
                    const float dx  = bx[s][j + 1] - mx1;
                    const float dy  = by[s][j + 1] - my1;
                    const float num = fabsf(dx * dy) + EPS;
                    const float den = (dx * dx + EPS) * (dy * dy + EPS);
                    a1 += num * __builtin_amdgcn_rsqf(den);
                }
            }
        }
        ch0[o] += fminf(fmaxf(a0 * (1.f / 25.f), 0.f), 1.f);
        ch1[o] += fminf(fmaxf(a1 * (1.f / 25.f), 0.f), 1.f);

        const int sO = o % 5;
        #pragma unroll
        for (int j = 0; j < 6; ++j) { csx[j] -= bx[sO][j]; csy[j] -= by[sO][j]; }
    }
}

__global__ __launch_bounds__(256, 2)
void zncc_kernel(const float* __restrict__ x,
                 const float* __restrict__ y,
                 float* __restrict__ out) {
    __shared__ float sb[2][2][LPAD];    // [buf][x=0/y=1][...]  40960 B

    const int tid = threadIdx.x;
    const int tx  = tid & 31;           // 32 col-pairs -> 64 cols
    const int ry  = tid >> 5;           // 0..7 -> rows 4*ry..4*ry+3
    const int cx  = 2 * tx;
    const int w0  = blockIdx.x * TW;
    const int h0  = blockIdx.y * TH;
    const int b   = blockIdx.z;

    // ---- staging address math, once (reused for all 3 channels) ----
    int   goff[NPF];
    float fm[NPF];
    #pragma unroll
    for (int k = 0; k < NPF; ++k) {
        const int i  = tid + 256 * k;
        const int l  = i / LW;
        const int m  = i - l * LW;
        const int gr = h0 + l - HALO;
        const int gc = w0 + m - HALO;
        const bool ok = (i < LSZ) && ((unsigned)gr < (unsigned)H) &&
                        ((unsigned)gc < (unsigned)W);
        goff[k] = ok ? gr * W + gc : 0;
        fm[k]   = ok ? 1.f : 0.f;
    }

    const float* xb0 = x + (size_t)(b * C) * PLANE;
    const float* yb0 = y + (size_t)(b * C) * PLANE;

    float ch0[4] = {0.f, 0.f, 0.f, 0.f};
    float ch1[4] = {0.f, 0.f, 0.f, 0.f};
    float px[NPF], py[NPF];

    // ---- stage channel 0 -> buf0 ----
    prefetch_plane(xb0, goff, fm, px);
    prefetch_plane(yb0, goff, fm, py);
    write_tile(&sb[0][0][0], px, tid);
    write_tile(&sb[0][1][0], py, tid);
    __syncthreads();

    // ---- channel 0: prefetch ch1, compute from buf0, write buf1 ----
    prefetch_plane(xb0 + PLANE, goff, fm, px);
    prefetch_plane(yb0 + PLANE, goff, fm, py);
    compute_channel(&sb[0][0][0], &sb[0][1][0], ry, cx, ch0, ch1);
    write_tile(&sb[1][0][0], px, tid);
    write_tile(&sb[1][1][0], py, tid);
    __syncthreads();

    // ---- channel 1: prefetch ch2, compute from buf1, write buf0 ----
    prefetch_plane(xb0 + 2 * PLANE, goff, fm, px);
    prefetch_plane(yb0 + 2 * PLANE, goff, fm, py);
    compute_channel(&sb[1][0][0], &sb[1][1][0], ry, cx, ch0, ch1);
    write_tile(&sb[0][0][0], px, tid);
    write_tile(&sb[0][1][0], py, tid);
    __syncthreads();

    // ---- channel 2: compute from buf0 ----
    compute_channel(&sb[0][0][0], &sb[0][1][0], ry, cx, ch0, ch1);

    // ---- write 2x4 output strip ----
    #pragma unroll
    for (int o = 0; o < 4; ++o) {
        float2 v;
        v.x = ch0[o] * (1.f / 3.f);
        v.y = ch1[o] * (1.f / 3.f);
        *reinterpret_cast<float2*>(
            &out[((size_t)b * H + h0 + 4 * ry + o) * W + w0 + cx]) = v;
    }
}

extern "C" void kernel_launch(void* const* d_in, const int* in_sizes, int n_in,
                              void* d_out, int out_size, void* d_ws, size_t ws_size,
                              hipStream_t stream) {
    const float* x = (const float*)d_in[0];
    const float* y = (const float*)d_in[1];
    float* out = (float*)d_out;
    dim3 grid(W / TW, H / TH, NB);   // 8, 16, 4 = 512 blocks (2 per CU)
    zncc_kernel<<<grid, dim3(256), 0, stream>>>(x, y, out);
}